// Round 3
// baseline (891.735 us; speedup 1.0000x reference)
//
#include <hip/hip_runtime.h>
#include <cstdint>
#include <cstddef>

// GCN 2-layer forward for MI355X.
// Sizes (from reference): N=100000 nodes, E=1600000 edges, IN_F=128, H_F=64, OUT_F=32.

#define IN_F 128
#define H_F 64
#define OUT_F 32

// ---------------- dtype detection for edge_index (int64 vs int32) -------------
// If the buffer really is int64, every value is in [0, N). If it is int32 data
// misread as int64, each 8-byte read combines two random indices -> >= 2^32
// with probability ~1 for at least one of 64 samples.
__global__ void k_detect_idx64(const long long* __restrict__ idx, int n_nodes,
                               int* __restrict__ flag) {
    __shared__ int ok;
    if (threadIdx.x == 0) ok = 1;
    __syncthreads();
    long long v = idx[threadIdx.x];  // first 64 values
    if (v < 0 || v >= (long long)n_nodes) atomicAnd(&ok, 0);
    __syncthreads();
    if (threadIdx.x == 0) *flag = ok;
}

// ---------------- degree / norm prep ----------------
__global__ void k_init_deg(float* __restrict__ deg, int n) {
    int i = blockIdx.x * blockDim.x + threadIdx.x;
    if (i < n) deg[i] = 1.0f;  // self-loop weight
}

__global__ void k_edge_prep(const long long* __restrict__ idx64, const float* __restrict__ ew,
                            int* __restrict__ row32, int* __restrict__ col32,
                            float* __restrict__ deg, const int* __restrict__ flag, int E) {
    int e = blockIdx.x * blockDim.x + threadIdx.x;
    if (e >= E) return;
    int r, c;
    if (*flag) {
        r = (int)idx64[e];
        c = (int)idx64[E + e];
    } else {
        const int* idx32 = (const int*)idx64;
        r = idx32[e];
        c = idx32[E + e];
    }
    row32[e] = r;
    col32[e] = c;
    atomicAdd(&deg[c], ew[e]);
}

__global__ void k_rsqrt_inplace(float* __restrict__ deg, int n) {
    int i = blockIdx.x * blockDim.x + threadIdx.x;
    if (i < n) deg[i] = rsqrtf(deg[i]);  // deg >= 1 always (self-loop)
}

__global__ void k_norm(const int* __restrict__ row32, const int* __restrict__ col32,
                       const float* __restrict__ ew, const float* __restrict__ dinv,
                       float* __restrict__ norm, int E) {
    int e = blockIdx.x * blockDim.x + threadIdx.x;
    if (e < E) norm[e] = dinv[row32[e]] * ew[e] * dinv[col32[e]];
}

// ---------------- dense GEMM: Y[N,F] = X[N,K] @ W[K,F], W staged in LDS ------
template <int K, int F>
__global__ void k_gemm(const float* __restrict__ X, const float* __restrict__ W,
                       float* __restrict__ Y, int N) {
    __shared__ float Ws[K * F];
    for (int t = threadIdx.x; t < (K * F) / 4; t += blockDim.x) {
        reinterpret_cast<float4*>(Ws)[t] = reinterpret_cast<const float4*>(W)[t];
    }
    __syncthreads();
    constexpr int NPI = 256 / F;      // nodes per pass
    constexpr int ITERS = 64 / NPI;   // 64 nodes per block
    const int f = threadIdx.x % F;
    const int nl = threadIdx.x / F;
    const int base = blockIdx.x * 64;
    for (int it = 0; it < ITERS; ++it) {
        int n = base + it * NPI + nl;
        if (n < N) {
            const float4* x4 = reinterpret_cast<const float4*>(X + (size_t)n * K);
            float acc = 0.f;
#pragma unroll
            for (int k4 = 0; k4 < K / 4; ++k4) {
                float4 xv = x4[k4];
                acc += xv.x * Ws[(4 * k4 + 0) * F + f];
                acc += xv.y * Ws[(4 * k4 + 1) * F + f];
                acc += xv.z * Ws[(4 * k4 + 2) * F + f];
                acc += xv.w * Ws[(4 * k4 + 3) * F + f];
            }
            Y[(size_t)n * F + f] = acc;
        }
    }
}

// ---------------- edge scatter: Agg[col] += norm * Hin[row] ------------------
template <int F>
__global__ void k_scatter(const int* __restrict__ row32, const int* __restrict__ col32,
                          const float* __restrict__ norm, const float* __restrict__ Hin,
                          float* __restrict__ Agg, int E) {
    int t = blockIdx.x * 256 + threadIdx.x;
    int e = t / F;
    int f = t % F;
    if (e < E) {
        float v = norm[e] * Hin[(size_t)row32[e] * F + f];
        atomicAdd(&Agg[(size_t)col32[e] * F + f], v);
    }
}

// ---------------- layer-1 epilogue: H = relu(agg + dinv^2*XW1 + b1) ----------
__global__ void k_bias_relu_self(float* __restrict__ H, const float* __restrict__ XW1,
                                 const float* __restrict__ dinv, const float* __restrict__ b1,
                                 int N) {
    int t = blockIdx.x * blockDim.x + threadIdx.x;
    if (t < N * H_F) {
        int n = t >> 6;  // / 64
        int f = t & 63;
        float d = dinv[n];
        float v = H[t] + d * d * XW1[t] + b1[f];
        H[t] = v > 0.f ? v : 0.f;
    }
}

// ---------------- layer-2 init: Out = dinv^2*HW2 + b2 (then scatter adds) ----
__global__ void k_out_init(float* __restrict__ Out, const float* __restrict__ HW2,
                           const float* __restrict__ dinv, const float* __restrict__ b2,
                           int N) {
    int t = blockIdx.x * blockDim.x + threadIdx.x;
    if (t < N * OUT_F) {
        int n = t >> 5;  // / 32
        int f = t & 31;
        float d = dinv[n];
        Out[t] = d * d * HW2[t] + b2[f];
    }
}

extern "C" void kernel_launch(void* const* d_in, const int* in_sizes, int n_in,
                              void* d_out, int out_size, void* d_ws, size_t ws_size,
                              hipStream_t stream) {
    const float* x = (const float*)d_in[0];
    const long long* idx = (const long long*)d_in[1];
    const float* ew = (const float*)d_in[2];
    const float* W1 = (const float*)d_in[3];
    const float* b1 = (const float*)d_in[4];
    const float* W2 = (const float*)d_in[5];
    const float* b2 = (const float*)d_in[6];
    float* out = (float*)d_out;

    const int N = in_sizes[0] / IN_F;   // 100000
    const int E = in_sizes[2];          // 1600000

    // workspace carve-up (256B aligned)
    char* ws = (char*)d_ws;
    size_t off = 0;
    auto alloc = [&](size_t bytes) {
        void* p = ws + off;
        off += (bytes + 255) & ~(size_t)255;
        return p;
    };
    int* row32 = (int*)alloc((size_t)E * 4);
    int* col32 = (int*)alloc((size_t)E * 4);
    float* norm = (float*)alloc((size_t)E * 4);
    float* dinv = (float*)alloc((size_t)N * 4);   // holds deg, then rsqrt in place
    int* flag = (int*)alloc(256);
    float* XW1 = (float*)alloc((size_t)N * H_F * 4);
    float* H = (float*)alloc((size_t)N * H_F * 4);    // agg1 then relu'd in place
    float* HW2 = (float*)alloc((size_t)N * OUT_F * 4);

    // ---- norm prep ----
    k_detect_idx64<<<1, 64, 0, stream>>>(idx, N, flag);
    k_init_deg<<<(N + 255) / 256, 256, 0, stream>>>(dinv, N);
    k_edge_prep<<<(E + 255) / 256, 256, 0, stream>>>(idx, ew, row32, col32, dinv, flag, E);
    k_rsqrt_inplace<<<(N + 255) / 256, 256, 0, stream>>>(dinv, N);
    k_norm<<<(E + 255) / 256, 256, 0, stream>>>(row32, col32, ew, dinv, norm, E);

    // ---- layer 1 ----
    k_gemm<IN_F, H_F><<<(N + 63) / 64, 256, 0, stream>>>(x, W1, XW1, N);
    hipMemsetAsync(H, 0, (size_t)N * H_F * 4, stream);
    {
        long long total = (long long)E * H_F;
        int grid = (int)((total + 255) / 256);
        k_scatter<H_F><<<grid, 256, 0, stream>>>(row32, col32, norm, XW1, H, E);
    }
    k_bias_relu_self<<<(N * H_F + 255) / 256, 256, 0, stream>>>(H, XW1, dinv, b1, N);

    // ---- layer 2 ----
    k_gemm<H_F, OUT_F><<<(N + 63) / 64, 256, 0, stream>>>(H, W2, HW2, N);
    k_out_init<<<(N * OUT_F + 255) / 256, 256, 0, stream>>>(out, HW2, dinv, b2, N);
    {
        long long total = (long long)E * OUT_F;
        int grid = (int)((total + 255) / 256);
        k_scatter<OUT_F><<<grid, 256, 0, stream>>>(row32, col32, norm, HW2, out, E);
    }
}

// Round 5
// 669.223 us; speedup vs baseline: 1.3325x; 1.3325x over previous
//
#include <hip/hip_runtime.h>
#include <cstdint>
#include <cstddef>

// GCN 2-layer forward for MI355X — CSR gather formulation (no hot-path atomics).
// N=100000, E=1600000, IN_F=128, H_F=64, OUT_F=32.

#define IN_F 128
#define H_F 64
#define OUT_F 32

// ---------------- dtype detection for edge_index (int64 vs int32) ------------
__global__ void k_detect_idx64(const long long* __restrict__ idx, int n_nodes,
                               int* __restrict__ flag) {
    __shared__ int ok;
    if (threadIdx.x == 0) ok = 1;
    __syncthreads();
    long long v = idx[threadIdx.x];  // first 64 values
    if (v < 0 || v >= (long long)n_nodes) atomicAnd(&ok, 0);
    __syncthreads();
    if (threadIdx.x == 0) *flag = ok;
}

__device__ __forceinline__ void decode_edge(const long long* __restrict__ idx64, int E,
                                            int e, int flag, int& r, int& c) {
    if (flag) {
        r = (int)idx64[e];
        c = (int)idx64[E + e];
    } else {
        const int* p = (const int*)idx64;
        r = p[e];
        c = p[E + e];
    }
}

// ---------------- histogram + weighted degree ---------------------------------
__global__ void k_edge_prep(const long long* __restrict__ idx64, const float* __restrict__ ew,
                            const int* __restrict__ flag, int* __restrict__ cnt,
                            float* __restrict__ deg, int E) {
    int e = blockIdx.x * 256 + threadIdx.x;
    if (e >= E) return;
    int r, c;
    decode_edge(idx64, E, e, *flag, r, c);
    atomicAdd(&cnt[c], 1);
    atomicAdd(&deg[c], ew[e]);
}

// dinv = rsqrt(deg + 1)   (+1 = self-loop weight)
__global__ void k_rsqrt(float* __restrict__ deg, int n) {
    int i = blockIdx.x * blockDim.x + threadIdx.x;
    if (i < n) deg[i] = rsqrtf(deg[i] + 1.0f);
}

// ---------------- exclusive scan over cnt[N] (3 kernels) ----------------------
__global__ void k_scan_partial(const int* __restrict__ cnt, int* __restrict__ partial, int n) {
    __shared__ int s[256];
    int i = blockIdx.x * 256 + threadIdx.x;
    s[threadIdx.x] = (i < n) ? cnt[i] : 0;
    __syncthreads();
    for (int st = 128; st > 0; st >>= 1) {
        if (threadIdx.x < st) s[threadIdx.x] += s[threadIdx.x + st];
        __syncthreads();
    }
    if (threadIdx.x == 0) partial[blockIdx.x] = s[0];
}

__global__ void k_scan_top(int* __restrict__ partial, int nparts) {  // exclusive, in place
    __shared__ int s[512];
    int t = threadIdx.x;
    int mine = (t < nparts) ? partial[t] : 0;
    s[t] = mine;
    __syncthreads();
    for (int st = 1; st < 512; st <<= 1) {
        int v = (t >= st) ? s[t - st] : 0;
        __syncthreads();
        s[t] += v;
        __syncthreads();
    }
    if (t < nparts) partial[t] = s[t] - mine;
}

__global__ void k_scan_final(const int* __restrict__ cnt, const int* __restrict__ partial,
                             int* __restrict__ off, int* __restrict__ cursor, int n) {
    __shared__ int s[256];
    int t = threadIdx.x;
    int i = blockIdx.x * 256 + t;
    int mine = (i < n) ? cnt[i] : 0;
    s[t] = mine;
    __syncthreads();
    for (int st = 1; st < 256; st <<= 1) {
        int v = (t >= st) ? s[t - st] : 0;
        __syncthreads();
        s[t] += v;
        __syncthreads();
    }
    if (i < n) {
        int ex = s[t] - mine + partial[blockIdx.x];
        off[i] = ex;
        cursor[i] = ex;
    }
}

// ---------------- CSR build: group edges by destination ----------------------
__global__ void k_reorder(const long long* __restrict__ idx64, const float* __restrict__ ew,
                          const int* __restrict__ flag, const float* __restrict__ dinv,
                          int* __restrict__ cursor, int* __restrict__ csr_row,
                          float* __restrict__ csr_val, int E) {
    int e = blockIdx.x * 256 + threadIdx.x;
    if (e >= E) return;
    int r, c;
    decode_edge(idx64, E, e, *flag, r, c);
    float v = dinv[r] * ew[e] * dinv[c];
    int pos = atomicAdd(&cursor[c], 1);
    csr_row[pos] = r;
    csr_val[pos] = v;
}

// ---------------- dense GEMM: Y[N,F] = X[N,K] @ W[K,F], W staged in LDS ------
template <int K, int F>
__global__ void k_gemm(const float* __restrict__ X, const float* __restrict__ W,
                       float* __restrict__ Y, int N) {
    __shared__ float Ws[K * F];
    for (int t = threadIdx.x; t < (K * F) / 4; t += blockDim.x) {
        reinterpret_cast<float4*>(Ws)[t] = reinterpret_cast<const float4*>(W)[t];
    }
    __syncthreads();
    constexpr int NPI = 256 / F;      // nodes per pass
    constexpr int ITERS = 64 / NPI;   // 64 nodes per block
    const int f = threadIdx.x % F;
    const int nl = threadIdx.x / F;
    const int base = blockIdx.x * 64;
    for (int it = 0; it < ITERS; ++it) {
        int n = base + it * NPI + nl;
        if (n < N) {
            const float4* x4 = reinterpret_cast<const float4*>(X + (size_t)n * K);
            float acc = 0.f;
#pragma unroll
            for (int k4 = 0; k4 < K / 4; ++k4) {
                float4 xv = x4[k4];
                acc += xv.x * Ws[(4 * k4 + 0) * F + f];
                acc += xv.y * Ws[(4 * k4 + 1) * F + f];
                acc += xv.z * Ws[(4 * k4 + 2) * F + f];
                acc += xv.w * Ws[(4 * k4 + 3) * F + f];
            }
            Y[(size_t)n * F + f] = acc;
        }
    }
}

// ---------------- gather aggregation: one F-lane group per node --------------
// Out[n] = (RELU?) ( dinv[n]^2 * Yin[n] + sum_j csr_val[j]*Yin[csr_row[j]] + bias )
template <int F, bool RELU>
__global__ void k_agg(const float* __restrict__ Yin, const int* __restrict__ off,
                      const int* __restrict__ cnt, const int* __restrict__ csr_row,
                      const float* __restrict__ csr_val, const float* __restrict__ dinv,
                      const float* __restrict__ bias, float* __restrict__ Out, int N) {
    const int lane = threadIdx.x % F;
    const int sub = threadIdx.x / F;
    const int n = blockIdx.x * (256 / F) + sub;
    if (n >= N) return;
    float d = dinv[n];
    float acc = d * d * Yin[(size_t)n * F + lane];
    int j = off[n];
    const int e = j + cnt[n];
    for (; j + 1 < e; j += 2) {
        int r0 = csr_row[j], r1 = csr_row[j + 1];
        float v0 = csr_val[j], v1 = csr_val[j + 1];
        acc += v0 * Yin[(size_t)r0 * F + lane];
        acc += v1 * Yin[(size_t)r1 * F + lane];
    }
    if (j < e) acc += csr_val[j] * Yin[(size_t)csr_row[j] * F + lane];
    acc += bias[lane];
    if (RELU) acc = acc > 0.f ? acc : 0.f;
    Out[(size_t)n * F + lane] = acc;
}

extern "C" void kernel_launch(void* const* d_in, const int* in_sizes, int n_in,
                              void* d_out, int out_size, void* d_ws, size_t ws_size,
                              hipStream_t stream) {
    const float* x = (const float*)d_in[0];
    const long long* idx = (const long long*)d_in[1];
    const float* ew = (const float*)d_in[2];
    const float* W1 = (const float*)d_in[3];
    const float* b1 = (const float*)d_in[4];
    const float* W2 = (const float*)d_in[5];
    const float* b2 = (const float*)d_in[6];
    float* out = (float*)d_out;

    const int N = in_sizes[0] / IN_F;   // 100000
    const int E = in_sizes[2];          // 1600000
    const int nparts = (N + 255) / 256; // 391 (<= 512 required by k_scan_top)

    // workspace carve-up (256B aligned)
    char* ws = (char*)d_ws;
    size_t off_b = 0;
    auto alloc = [&](size_t bytes) {
        void* p = ws + off_b;
        off_b += (bytes + 255) & ~(size_t)255;
        return p;
    };
    int* cnt = (int*)alloc((size_t)N * 4);
    float* dinv = (float*)alloc((size_t)N * 4);   // deg, then rsqrt in place
    int* offs = (int*)alloc((size_t)N * 4);
    int* cursor = (int*)alloc((size_t)N * 4);
    int* partial = (int*)alloc((size_t)nparts * 4);
    int* flag = (int*)alloc(256);
    int* csr_row = (int*)alloc((size_t)E * 4);
    float* csr_val = (float*)alloc((size_t)E * 4);
    float* XW1 = (float*)alloc((size_t)N * H_F * 4);
    float* H = (float*)alloc((size_t)N * H_F * 4);
    float* HW2 = (float*)alloc((size_t)N * OUT_F * 4);

    // ---- CSR + norm prep ----
    k_detect_idx64<<<1, 64, 0, stream>>>(idx, N, flag);
    hipMemsetAsync(cnt, 0, (size_t)N * 4, stream);
    hipMemsetAsync(dinv, 0, (size_t)N * 4, stream);
    k_edge_prep<<<(E + 255) / 256, 256, 0, stream>>>(idx, ew, flag, cnt, dinv, E);
    k_rsqrt<<<(N + 255) / 256, 256, 0, stream>>>(dinv, N);
    k_scan_partial<<<nparts, 256, 0, stream>>>(cnt, partial, N);
    k_scan_top<<<1, 512, 0, stream>>>(partial, nparts);
    k_scan_final<<<nparts, 256, 0, stream>>>(cnt, partial, offs, cursor, N);
    k_reorder<<<(E + 255) / 256, 256, 0, stream>>>(idx, ew, flag, dinv, cursor, csr_row, csr_val, E);

    // ---- layer 1: H = relu(D^-1/2 A D^-1/2 (x@W1) + b1) ----
    k_gemm<IN_F, H_F><<<(N + 63) / 64, 256, 0, stream>>>(x, W1, XW1, N);
    k_agg<H_F, true><<<(N + 3) / 4, 256, 0, stream>>>(XW1, offs, cnt, csr_row, csr_val, dinv, b1, H, N);

    // ---- layer 2: out = D^-1/2 A D^-1/2 (H@W2) + b2 ----
    k_gemm<H_F, OUT_F><<<(N + 63) / 64, 256, 0, stream>>>(H, W2, HW2, N);
    k_agg<OUT_F, false><<<(N + 7) / 8, 256, 0, stream>>>(HW2, offs, cnt, csr_row, csr_val, dinv, b2, out, N);
}

// Round 8
// 558.888 us; speedup vs baseline: 1.5956x; 1.1974x over previous
//
#include <hip/hip_runtime.h>
#include <cstdint>
#include <cstddef>

// GCN 2-layer forward for MI355X — CSR gather formulation, packed atomics.
// N=100000, E=1600000, IN_F=128, H_F=64, OUT_F=32.

#define IN_F 128
#define H_F 64
#define OUT_F 32

// Fixed-point scale for degree accumulation (low 40 bits of packed u64).
#define DEG_SCALE 16777216.0f  // 2^24
#define DEG_MASK ((1ULL << 40) - 1)

// ---------------- dtype detection for edge_index (int64 vs int32) ------------
__global__ void k_detect_idx64(const long long* __restrict__ idx, int n_nodes,
                               int* __restrict__ flag) {
    __shared__ int ok;
    if (threadIdx.x == 0) ok = 1;
    __syncthreads();
    long long v = idx[threadIdx.x];  // first 64 values
    if (v < 0 || v >= (long long)n_nodes) atomicAnd(&ok, 0);
    __syncthreads();
    if (threadIdx.x == 0) *flag = ok;
}

__device__ __forceinline__ void decode_edge(const long long* __restrict__ idx64, int E,
                                            int e, int flag, int& r, int& c) {
    if (flag) {
        r = (int)idx64[e];
        c = (int)idx64[E + e];
    } else {
        const int* p = (const int*)idx64;
        r = p[e];
        c = p[E + e];
    }
}

// ---------------- histogram + weighted degree: ONE u64 atomic per edge --------
// packed[c] += (1<<40) | fix24(ew)   => count in high bits, weight sum in low.
__global__ void k_edge_prep(const long long* __restrict__ idx64, const float* __restrict__ ew,
                            const int* __restrict__ flag,
                            unsigned long long* __restrict__ deg_cnt, int E) {
    int e = blockIdx.x * 256 + threadIdx.x;
    if (e >= E) return;
    int r, c;
    decode_edge(idx64, E, e, *flag, r, c);
    unsigned long long w = (unsigned long long)(ew[e] * DEG_SCALE + 0.5f);
    atomicAdd(&deg_cnt[c], (1ULL << 40) | w);
}

// unpack: cnt[i] = count; dinv[i] = rsqrt(deg + 1)  (+1 = self-loop weight)
__global__ void k_unpack(const unsigned long long* __restrict__ deg_cnt,
                         int* __restrict__ cnt, float* __restrict__ dinv, int n) {
    int i = blockIdx.x * blockDim.x + threadIdx.x;
    if (i < n) {
        unsigned long long p = deg_cnt[i];
        cnt[i] = (int)(p >> 40);
        float deg = (float)(p & DEG_MASK) * (1.0f / DEG_SCALE);
        dinv[i] = rsqrtf(deg + 1.0f);
    }
}

// ---------------- exclusive scan over cnt[N] (3 kernels) ----------------------
__global__ void k_scan_partial(const int* __restrict__ cnt, int* __restrict__ partial, int n) {
    __shared__ int s[256];
    int i = blockIdx.x * 256 + threadIdx.x;
    s[threadIdx.x] = (i < n) ? cnt[i] : 0;
    __syncthreads();
    for (int st = 128; st > 0; st >>= 1) {
        if (threadIdx.x < st) s[threadIdx.x] += s[threadIdx.x + st];
        __syncthreads();
    }
    if (threadIdx.x == 0) partial[blockIdx.x] = s[0];
}

__global__ void k_scan_top(int* __restrict__ partial, int nparts) {  // exclusive, in place
    __shared__ int s[512];
    int t = threadIdx.x;
    int mine = (t < nparts) ? partial[t] : 0;
    s[t] = mine;
    __syncthreads();
    for (int st = 1; st < 512; st <<= 1) {
        int v = (t >= st) ? s[t - st] : 0;
        __syncthreads();
        s[t] += v;
        __syncthreads();
    }
    if (t < nparts) partial[t] = s[t] - mine;
}

__global__ void k_scan_final(const int* __restrict__ cnt, const int* __restrict__ partial,
                             int* __restrict__ off, int* __restrict__ cursor, int n) {
    __shared__ int s[256];
    int t = threadIdx.x;
    int i = blockIdx.x * 256 + t;
    int mine = (i < n) ? cnt[i] : 0;
    s[t] = mine;
    __syncthreads();
    for (int st = 1; st < 256; st <<= 1) {
        int v = (t >= st) ? s[t - st] : 0;
        __syncthreads();
        s[t] += v;
        __syncthreads();
    }
    if (i < n) {
        int ex = s[t] - mine + partial[blockIdx.x];
        off[i] = ex;
        cursor[i] = ex;
    }
}

// ---------------- CSR build: group edges by destination, packed 8B stores ----
__global__ void k_reorder(const long long* __restrict__ idx64, const float* __restrict__ ew,
                          const int* __restrict__ flag, const float* __restrict__ dinv,
                          int* __restrict__ cursor, int2* __restrict__ csr, int E) {
    int e = blockIdx.x * 256 + threadIdx.x;
    if (e >= E) return;
    int r, c;
    decode_edge(idx64, E, e, *flag, r, c);
    float v = dinv[r] * ew[e] * dinv[c];
    int pos = atomicAdd(&cursor[c], 1);
    csr[pos] = make_int2(r, __float_as_int(v));
}

// ---------------- dense GEMM: Y[N,F] = X[N,K] @ W[K,F], W staged in LDS ------
template <int K, int F>
__global__ void k_gemm(const float* __restrict__ X, const float* __restrict__ W,
                       float* __restrict__ Y, int N) {
    __shared__ float Ws[K * F];
    for (int t = threadIdx.x; t < (K * F) / 4; t += blockDim.x) {
        reinterpret_cast<float4*>(Ws)[t] = reinterpret_cast<const float4*>(W)[t];
    }
    __syncthreads();
    constexpr int NPI = 256 / F;      // nodes per pass
    constexpr int ITERS = 64 / NPI;   // 64 nodes per block
    const int f = threadIdx.x % F;
    const int nl = threadIdx.x / F;
    const int base = blockIdx.x * 64;
    for (int it = 0; it < ITERS; ++it) {
        int n = base + it * NPI + nl;
        if (n < N) {
            const float4* x4 = reinterpret_cast<const float4*>(X + (size_t)n * K);
            float acc = 0.f;
#pragma unroll
            for (int k4 = 0; k4 < K / 4; ++k4) {
                float4 xv = x4[k4];
                acc += xv.x * Ws[(4 * k4 + 0) * F + f];
                acc += xv.y * Ws[(4 * k4 + 1) * F + f];
                acc += xv.z * Ws[(4 * k4 + 2) * F + f];
                acc += xv.w * Ws[(4 * k4 + 3) * F + f];
            }
            Y[(size_t)n * F + f] = acc;
        }
    }
}

// ---------------- gather aggregation: one F-lane group per node --------------
// Out[n] = (RELU?) ( dinv[n]^2 * Yin[n] + sum_j val_j * Yin[row_j] + bias )
template <int F, bool RELU>
__global__ void k_agg(const float* __restrict__ Yin, const int* __restrict__ off,
                      const int* __restrict__ cnt, const int2* __restrict__ csr,
                      const float* __restrict__ dinv, const float* __restrict__ bias,
                      float* __restrict__ Out, int N) {
    const int lane = threadIdx.x % F;
    const int sub = threadIdx.x / F;
    const int n = blockIdx.x * (256 / F) + sub;
    if (n >= N) return;
    float d = dinv[n];
    float acc = d * d * Yin[(size_t)n * F + lane];
    int j = off[n];
    const int e = j + cnt[n];
    for (; j + 1 < e; j += 2) {
        int2 c0 = csr[j], c1 = csr[j + 1];
        acc += __int_as_float(c0.y) * Yin[(size_t)c0.x * F + lane];
        acc += __int_as_float(c1.y) * Yin[(size_t)c1.x * F + lane];
    }
    if (j < e) {
        int2 c0 = csr[j];
        acc += __int_as_float(c0.y) * Yin[(size_t)c0.x * F + lane];
    }
    acc += bias[lane];
    if (RELU) acc = acc > 0.f ? acc : 0.f;
    Out[(size_t)n * F + lane] = acc;
}

extern "C" void kernel_launch(void* const* d_in, const int* in_sizes, int n_in,
                              void* d_out, int out_size, void* d_ws, size_t ws_size,
                              hipStream_t stream) {
    const float* x = (const float*)d_in[0];
    const long long* idx = (const long long*)d_in[1];
    const float* ew = (const float*)d_in[2];
    const float* W1 = (const float*)d_in[3];
    const float* b1 = (const float*)d_in[4];
    const float* W2 = (const float*)d_in[5];
    const float* b2 = (const float*)d_in[6];
    float* out = (float*)d_out;

    const int N = in_sizes[0] / IN_F;   // 100000
    const int E = in_sizes[2];          // 1600000
    const int nparts = (N + 255) / 256; // 391 (<= 512 required by k_scan_top)

    // workspace carve-up (256B aligned)
    char* ws = (char*)d_ws;
    size_t off_b = 0;
    auto alloc = [&](size_t bytes) {
        void* p = ws + off_b;
        off_b += (bytes + 255) & ~(size_t)255;
        return p;
    };
    unsigned long long* deg_cnt = (unsigned long long*)alloc((size_t)N * 8);
    int* cnt = (int*)alloc((size_t)N * 4);
    float* dinv = (float*)alloc((size_t)N * 4);
    int* offs = (int*)alloc((size_t)N * 4);
    int* cursor = (int*)alloc((size_t)N * 4);
    int* partial = (int*)alloc((size_t)nparts * 4);
    int* flag = (int*)alloc(256);
    int2* csr = (int2*)alloc((size_t)E * 8);
    float* XW1 = (float*)alloc((size_t)N * H_F * 4);
    float* H = (float*)alloc((size_t)N * H_F * 4);
    float* HW2 = (float*)alloc((size_t)N * OUT_F * 4);

    // ---- CSR + norm prep ----
    k_detect_idx64<<<1, 64, 0, stream>>>(idx, N, flag);
    hipMemsetAsync(deg_cnt, 0, (size_t)N * 8, stream);
    k_edge_prep<<<(E + 255) / 256, 256, 0, stream>>>(idx, ew, flag, deg_cnt, E);
    k_unpack<<<(N + 255) / 256, 256, 0, stream>>>(deg_cnt, cnt, dinv, N);
    k_scan_partial<<<nparts, 256, 0, stream>>>(cnt, partial, N);
    k_scan_top<<<1, 512, 0, stream>>>(partial, nparts);
    k_scan_final<<<nparts, 256, 0, stream>>>(cnt, partial, offs, cursor, N);
    k_reorder<<<(E + 255) / 256, 256, 0, stream>>>(idx, ew, flag, dinv, cursor, csr, E);

    // ---- layer 1: H = relu(D^-1/2 A D^-1/2 (x@W1) + b1) ----
    k_gemm<IN_F, H_F><<<(N + 63) / 64, 256, 0, stream>>>(x, W1, XW1, N);
    k_agg<H_F, true><<<(N + 3) / 4, 256, 0, stream>>>(XW1, offs, cnt, csr, dinv, b1, H, N);

    // ---- layer 2: out = D^-1/2 A D^-1/2 (H@W2) + b2 ----
    k_gemm<H_F, OUT_F><<<(N + 63) / 64, 256, 0, stream>>>(H, W2, HW2, N);
    k_agg<OUT_F, false><<<(N + 7) / 8, 256, 0, stream>>>(HW2, offs, cnt, csr, dinv, b2, out, N);
}

// Round 11
// 516.455 us; speedup vs baseline: 1.7266x; 1.0822x over previous
//
#include <hip/hip_runtime.h>
#include <cstdint>
#include <cstddef>

// GCN 2-layer forward for MI355X — CSR gather + register-tiled GEMM.
// N=100000, E=1600000, IN_F=128, H_F=64, OUT_F=32.

#define IN_F 128
#define H_F 64
#define OUT_F 32

// Fixed-point scale for degree accumulation (low 40 bits of packed u64).
#define DEG_SCALE 16777216.0f  // 2^24
#define DEG_MASK ((1ULL << 40) - 1)

// ---------------- dtype detection for edge_index (int64 vs int32) ------------
__global__ void k_detect_idx64(const long long* __restrict__ idx, int n_nodes,
                               int* __restrict__ flag) {
    __shared__ int ok;
    if (threadIdx.x == 0) ok = 1;
    __syncthreads();
    long long v = idx[threadIdx.x];  // first 64 values
    if (v < 0 || v >= (long long)n_nodes) atomicAnd(&ok, 0);
    __syncthreads();
    if (threadIdx.x == 0) *flag = ok;
}

__device__ __forceinline__ void decode_edge(const long long* __restrict__ idx64, int E,
                                            int e, int flag, int& r, int& c) {
    if (flag) {
        r = (int)idx64[e];
        c = (int)idx64[E + e];
    } else {
        const int* p = (const int*)idx64;
        r = p[e];
        c = p[E + e];
    }
}

// ---------------- histogram + weighted degree: ONE u64 atomic per edge --------
__global__ void k_edge_prep(const long long* __restrict__ idx64, const float* __restrict__ ew,
                            const int* __restrict__ flag,
                            unsigned long long* __restrict__ deg_cnt, int E) {
    int e = blockIdx.x * 256 + threadIdx.x;
    if (e >= E) return;
    int r, c;
    decode_edge(idx64, E, e, *flag, r, c);
    unsigned long long w = (unsigned long long)(ew[e] * DEG_SCALE + 0.5f);
    atomicAdd(&deg_cnt[c], (1ULL << 40) | w);
}

// unpack: cnt[i] = count; dinv[i] = rsqrt(deg + 1)  (+1 = self-loop weight)
__global__ void k_unpack(const unsigned long long* __restrict__ deg_cnt,
                         int* __restrict__ cnt, float* __restrict__ dinv, int n) {
    int i = blockIdx.x * blockDim.x + threadIdx.x;
    if (i < n) {
        unsigned long long p = deg_cnt[i];
        cnt[i] = (int)(p >> 40);
        float deg = (float)(p & DEG_MASK) * (1.0f / DEG_SCALE);
        dinv[i] = rsqrtf(deg + 1.0f);
    }
}

// ---------------- exclusive scan over cnt[N] (3 kernels) ----------------------
__global__ void k_scan_partial(const int* __restrict__ cnt, int* __restrict__ partial, int n) {
    __shared__ int s[256];
    int i = blockIdx.x * 256 + threadIdx.x;
    s[threadIdx.x] = (i < n) ? cnt[i] : 0;
    __syncthreads();
    for (int st = 128; st > 0; st >>= 1) {
        if (threadIdx.x < st) s[threadIdx.x] += s[threadIdx.x + st];
        __syncthreads();
    }
    if (threadIdx.x == 0) partial[blockIdx.x] = s[0];
}

__global__ void k_scan_top(int* __restrict__ partial, int nparts) {  // exclusive, in place
    __shared__ int s[512];
    int t = threadIdx.x;
    int mine = (t < nparts) ? partial[t] : 0;
    s[t] = mine;
    __syncthreads();
    for (int st = 1; st < 512; st <<= 1) {
        int v = (t >= st) ? s[t - st] : 0;
        __syncthreads();
        s[t] += v;
        __syncthreads();
    }
    if (t < nparts) partial[t] = s[t] - mine;
}

__global__ void k_scan_final(const int* __restrict__ cnt, const int* __restrict__ partial,
                             int* __restrict__ off, int* __restrict__ cursor, int n) {
    __shared__ int s[256];
    int t = threadIdx.x;
    int i = blockIdx.x * 256 + t;
    int mine = (i < n) ? cnt[i] : 0;
    s[t] = mine;
    __syncthreads();
    for (int st = 1; st < 256; st <<= 1) {
        int v = (t >= st) ? s[t - st] : 0;
        __syncthreads();
        s[t] += v;
        __syncthreads();
    }
    if (i < n) {
        int ex = s[t] - mine + partial[blockIdx.x];
        off[i] = ex;
        cursor[i] = ex;
    }
}

// ---------------- CSR build: group edges by destination, packed 8B stores ----
__global__ void k_reorder(const long long* __restrict__ idx64, const float* __restrict__ ew,
                          const int* __restrict__ flag, const float* __restrict__ dinv,
                          int* __restrict__ cursor, int2* __restrict__ csr, int E) {
    int e = blockIdx.x * 256 + threadIdx.x;
    if (e >= E) return;
    int r, c;
    decode_edge(idx64, E, e, *flag, r, c);
    float v = dinv[r] * ew[e] * dinv[c];
    int pos = atomicAdd(&cursor[c], 1);
    csr[pos] = make_int2(r, __float_as_int(v));
}

// ---------------- register-tiled GEMM: Y[N,F] = X[N,K] @ W[K,F] --------------
// Block: 256 threads, 128-row x F-col tile. X k-chunk staged transposed in LDS
// (Xs[k][row], row dim padded to 132 for bank-conflict-free b128 reads);
// W staged fully in LDS. Thread computes RPT rows x 4 cols in registers.
template <int K, int F>
__global__ __launch_bounds__(256) void k_gemm(const float* __restrict__ X,
                                              const float* __restrict__ W,
                                              float* __restrict__ Y, int N) {
    constexpr int KC = 32;             // k-chunk
    constexpr int TC = F / 4;          // col groups (16 or 8)
    constexpr int TR = 256 / TC;       // row groups (16 or 32)
    constexpr int RPT = 128 / TR;      // rows per thread (8 or 4)
    constexpr int XP = 132;            // padded row length (16B aligned, bank-spread)
    __shared__ float Xs[KC][XP];
    __shared__ float Ws[K * F];

    for (int t = threadIdx.x; t < (K * F) / 4; t += 256)
        reinterpret_cast<float4*>(Ws)[t] = reinterpret_cast<const float4*>(W)[t];

    const int tc = threadIdx.x % TC;
    const int tr = threadIdx.x / TC;
    const int row0 = blockIdx.x * 128;

    float acc[RPT][4];
#pragma unroll
    for (int i = 0; i < RPT; ++i)
#pragma unroll
        for (int j = 0; j < 4; ++j) acc[i][j] = 0.f;

    for (int kc = 0; kc < K; kc += KC) {
        __syncthreads();
        // stage X[row0..row0+127][kc..kc+KC) transposed -> Xs[k][row]
#pragma unroll
        for (int t = threadIdx.x; t < 128 * (KC / 4); t += 256) {
            int r = t / (KC / 4);
            int k4 = t % (KC / 4);
            int n = row0 + r;
            float4 v = (n < N) ? *reinterpret_cast<const float4*>(X + (size_t)n * K + kc + k4 * 4)
                               : make_float4(0.f, 0.f, 0.f, 0.f);
            Xs[k4 * 4 + 0][r] = v.x;
            Xs[k4 * 4 + 1][r] = v.y;
            Xs[k4 * 4 + 2][r] = v.z;
            Xs[k4 * 4 + 3][r] = v.w;
        }
        __syncthreads();
#pragma unroll
        for (int k = 0; k < KC; ++k) {
            float4 w = *reinterpret_cast<const float4*>(&Ws[(kc + k) * F + tc * 4]);
            float xr[RPT];
#pragma unroll
            for (int i = 0; i < RPT / 4; ++i) {
                float4 xv = *reinterpret_cast<const float4*>(&Xs[k][tr * RPT + i * 4]);
                xr[i * 4 + 0] = xv.x;
                xr[i * 4 + 1] = xv.y;
                xr[i * 4 + 2] = xv.z;
                xr[i * 4 + 3] = xv.w;
            }
#pragma unroll
            for (int i = 0; i < RPT; ++i) {
                acc[i][0] += xr[i] * w.x;
                acc[i][1] += xr[i] * w.y;
                acc[i][2] += xr[i] * w.z;
                acc[i][3] += xr[i] * w.w;
            }
        }
    }
    // store: float4 per row
#pragma unroll
    for (int i = 0; i < RPT; ++i) {
        int n = row0 + tr * RPT + i;
        if (n < N) {
            float4 v = make_float4(acc[i][0], acc[i][1], acc[i][2], acc[i][3]);
            *reinterpret_cast<float4*>(Y + (size_t)n * F + tc * 4) = v;
        }
    }
}

// ---------------- gather aggregation: one F-lane group per node --------------
// Out[n] = (RELU?) ( dinv[n]^2 * Yin[n] + sum_j val_j * Yin[row_j] + bias )
template <int F, bool RELU>
__global__ void k_agg(const float* __restrict__ Yin, const int* __restrict__ off,
                      const int* __restrict__ cnt, const int2* __restrict__ csr,
                      const float* __restrict__ dinv, const float* __restrict__ bias,
                      float* __restrict__ Out, int N) {
    const int lane = threadIdx.x % F;
    const int sub = threadIdx.x / F;
    const int n = blockIdx.x * (256 / F) + sub;
    if (n >= N) return;
    float d = dinv[n];
    float acc = d * d * Yin[(size_t)n * F + lane];
    int j = off[n];
    const int e = j + cnt[n];
    for (; j + 1 < e; j += 2) {
        int2 c0 = csr[j], c1 = csr[j + 1];
        acc += __int_as_float(c0.y) * Yin[(size_t)c0.x * F + lane];
        acc += __int_as_float(c1.y) * Yin[(size_t)c1.x * F + lane];
    }
    if (j < e) {
        int2 c0 = csr[j];
        acc += __int_as_float(c0.y) * Yin[(size_t)c0.x * F + lane];
    }
    acc += bias[lane];
    if (RELU) acc = acc > 0.f ? acc : 0.f;
    Out[(size_t)n * F + lane] = acc;
}

extern "C" void kernel_launch(void* const* d_in, const int* in_sizes, int n_in,
                              void* d_out, int out_size, void* d_ws, size_t ws_size,
                              hipStream_t stream) {
    const float* x = (const float*)d_in[0];
    const long long* idx = (const long long*)d_in[1];
    const float* ew = (const float*)d_in[2];
    const float* W1 = (const float*)d_in[3];
    const float* b1 = (const float*)d_in[4];
    const float* W2 = (const float*)d_in[5];
    const float* b2 = (const float*)d_in[6];
    float* out = (float*)d_out;

    const int N = in_sizes[0] / IN_F;   // 100000
    const int E = in_sizes[2];          // 1600000
    const int nparts = (N + 255) / 256; // 391 (<= 512 required by k_scan_top)

    // workspace carve-up (256B aligned)
    char* ws = (char*)d_ws;
    size_t off_b = 0;
    auto alloc = [&](size_t bytes) {
        void* p = ws + off_b;
        off_b += (bytes + 255) & ~(size_t)255;
        return p;
    };
    unsigned long long* deg_cnt = (unsigned long long*)alloc((size_t)N * 8);
    int* cnt = (int*)alloc((size_t)N * 4);
    float* dinv = (float*)alloc((size_t)N * 4);
    int* offs = (int*)alloc((size_t)N * 4);
    int* cursor = (int*)alloc((size_t)N * 4);
    int* partial = (int*)alloc((size_t)nparts * 4);
    int* flag = (int*)alloc(256);
    int2* csr = (int2*)alloc((size_t)E * 8);
    float* XW1 = (float*)alloc((size_t)N * H_F * 4);
    float* H = (float*)alloc((size_t)N * H_F * 4);
    float* HW2 = (float*)alloc((size_t)N * OUT_F * 4);

    // ---- CSR + norm prep ----
    k_detect_idx64<<<1, 64, 0, stream>>>(idx, N, flag);
    hipMemsetAsync(deg_cnt, 0, (size_t)N * 8, stream);
    k_edge_prep<<<(E + 255) / 256, 256, 0, stream>>>(idx, ew, flag, deg_cnt, E);
    k_unpack<<<(N + 255) / 256, 256, 0, stream>>>(deg_cnt, cnt, dinv, N);
    k_scan_partial<<<nparts, 256, 0, stream>>>(cnt, partial, N);
    k_scan_top<<<1, 512, 0, stream>>>(partial, nparts);
    k_scan_final<<<nparts, 256, 0, stream>>>(cnt, partial, offs, cursor, N);
    k_reorder<<<(E + 255) / 256, 256, 0, stream>>>(idx, ew, flag, dinv, cursor, csr, E);

    // ---- layer 1: H = relu(D^-1/2 A D^-1/2 (x@W1) + b1) ----
    k_gemm<IN_F, H_F><<<(N + 127) / 128, 256, 0, stream>>>(x, W1, XW1, N);
    k_agg<H_F, true><<<(N + 3) / 4, 256, 0, stream>>>(XW1, offs, cnt, csr, dinv, b1, H, N);

    // ---- layer 2: out = D^-1/2 A D^-1/2 (H@W2) + b2 ----
    k_gemm<H_F, OUT_F><<<(N + 127) / 128, 256, 0, stream>>>(H, W2, HW2, N);
    k_agg<OUT_F, false><<<(N + 7) / 8, 256, 0, stream>>>(HW2, offs, cnt, csr, dinv, b2, out, N);
}